// Round 20
// baseline (213.384 us; speedup 1.0000x reference)
//
#include <hip/hip_runtime.h>
#include <math.h>

#define B 2048
#define D 64
#define G 256           // z-grid points for the F_d(z) table
#define NCH 32          // j-chunks for the table build
#define NC2 16          // j-chunks for the MFMA/LSE role (128 j each)
#define NBLK 2048       // (G/4) tgroups x 32 chunks
#define NTG (G / 4)     // 64 t-groups (4 t per block)

#define ZLO (-5.5f)
#define DZ  (11.0f / 255.0f)
#define INVDZ (255.0f / 11.0f)

typedef float v2f  __attribute__((ext_vector_type(2)));
typedef short bf16x8 __attribute__((ext_vector_type(8)));
typedef float f32x4  __attribute__((ext_vector_type(4)));

static __device__ __forceinline__ float exp2fast(float x) { return __builtin_amdgcn_exp2f(x); }
static __device__ __forceinline__ float log2fast(float x) { return __builtin_amdgcn_logf(x); }
static __device__ __forceinline__ unsigned short f2bf(float x) {
    unsigned u = __float_as_uint(x);
    u += 0x7fff + ((u >> 16) & 1);          // RNE; inputs are finite
    return (unsigned short)(u >> 16);
}

// ---------------------------------------------------------------------------
// Kernel 1: per-(j,d) constants (log2 units):  lp2 = h*z^2 + g*z + q
//   h = -0.5*log2e*exp(-lv), g = -2*mu*h, q = mu^2*h + c
// packhg[j*D+d] = { bf16(h)<<16 | bf16(g), fp32 q }  (8B)
// Zx/Wt = bf16 MFMA operands; QQ[j]=sum_d q; kl partials -> klp;
// out zeroed; t-group counters zeroed (graph-replay safe).
// ---------------------------------------------------------------------------
__global__ __launch_bounds__(256) void k_pre(
    const float* __restrict__ kl, const float* __restrict__ zm,
    const float* __restrict__ zlv, const float* __restrict__ zs,
    uint2* __restrict__ packhg, unsigned short* __restrict__ Zx,
    unsigned short* __restrict__ Wt, float* __restrict__ QQ,
    float* __restrict__ klp, int* __restrict__ cnt, float* __restrict__ out)
{
    const float LOG2E   = 1.4426950408889634f;
    const float LOG_2PI = 1.8378770664093453f;
    __shared__ float red[4];
    int wv = threadIdx.x >> 6, d = threadIdx.x & 63;
    int j = blockIdx.x * 4 + wv;
    int idx = j * D + d;
    float lv = zlv[idx];
    float mu = zm[idx];
    float zz = zs[idx];
    float is = exp2fast(-LOG2E * lv);            // e^{-lv}
    float h  = -0.5f * LOG2E * is;
    float cv = -0.5f * LOG2E * (lv + LOG_2PI);
    float g  = -2.0f * mu * h;
    float q  = fmaf(mu * mu, h, cv);
    packhg[idx] = make_uint2(((unsigned)f2bf(h) << 16) | f2bf(g),
                             __float_as_uint(q));
    Wt[j * 128 + d]      = f2bf(h);
    Wt[j * 128 + 64 + d] = f2bf(g);
    Zx[j * 128 + d]      = f2bf(zz * zz);
    Zx[j * 128 + 64 + d] = f2bf(zz);

    float qs = q, ks = kl[idx];
#pragma unroll
    for (int off = 32; off; off >>= 1) {
        qs += __shfl_xor(qs, off);
        ks += __shfl_xor(ks, off);
    }
    if (d == 0) { QQ[j] = qs; red[wv] = ks; }
    __syncthreads();
    if (threadIdx.x == 0) {
        klp[blockIdx.x] = red[0] + red[1] + red[2] + red[3];  // kl partial
        if (blockIdx.x == 0) out[0] = 0.0f;                   // zero output
    }
    if (blockIdx.x == 0 && threadIdx.x < NTG)
        cnt[threadIdx.x] = 0;                                 // zero counters
}

// ---------------------------------------------------------------------------
// Role B (lse) — r17-proven, UNTOUCHED: one wave = 16-i x 128-j unit
// (NC2=16, 2048 units, wave 0 of each block). 8 j-tiles x 4 K-steps MFMA,
// online row-LSE, 16-lane butterfly.
// C/D: col = lane&15 (j), row = (lane>>4)*4 + reg (i)  [m89-verified].
// ---------------------------------------------------------------------------
static __device__ __forceinline__ void role_lse(
    int lw, const unsigned short* __restrict__ Zx,
    const unsigned short* __restrict__ Wt, const float* __restrict__ QQ,
    float* __restrict__ wsM, float* __restrict__ wsL)
{
    int lane  = threadIdx.x & 63;
    int i0    = (lw >> 4) * 16;
    int chunk = lw & 15;               // 0..15
    int jbase = chunk * 128;
    int r16 = lane & 15, kg = lane >> 4;

    const bf16x8* Za = (const bf16x8*)(Zx + (size_t)(i0 + r16) * 128 + kg * 8);
    bf16x8 a[4];
#pragma unroll
    for (int s = 0; s < 4; ++s) a[s] = Za[s * 4];   // stride 32 bf16 per K-step

    float m[4], l[4];
#pragma unroll
    for (int r = 0; r < 4; ++r) { m[r] = -3.0e38f; l[r] = 0.0f; }

    for (int t = 0; t < 8; ++t) {
        int j = jbase + t * 16 + r16;
        const bf16x8* Wb = (const bf16x8*)(Wt + (size_t)j * 128 + kg * 8);
        f32x4 c = (f32x4){0.0f, 0.0f, 0.0f, 0.0f};
#pragma unroll
        for (int s = 0; s < 4; ++s)
            c = __builtin_amdgcn_mfma_f32_16x16x32_bf16(a[s], Wb[s * 4], c, 0, 0, 0);
        float qq = QQ[j];
#pragma unroll
        for (int r = 0; r < 4; ++r) {
            float val = c[r] + qq;
            float delta = val - m[r];
            float e = exp2fast(-fabsf(delta));
            l[r] = (delta <= 0.0f) ? (l[r] + e) : fmaf(l[r], e, 1.0f);
            m[r] = fmaxf(m[r], val);
        }
    }
#pragma unroll
    for (int off = 8; off; off >>= 1) {
#pragma unroll
        for (int r = 0; r < 4; ++r) {
            float m2 = __shfl_xor(m[r], off);
            float l2 = __shfl_xor(l[r], off);
            float M  = fmaxf(m[r], m2);
            l[r] = fmaf(l[r], exp2fast(m[r] - M), l2 * exp2fast(m2 - M));
            m[r] = M;
        }
    }
    if (r16 == 0) {
#pragma unroll
        for (int r = 0; r < 4; ++r) {
            int i = i0 + kg * 4 + r;
            wsM[i * NC2 + chunk] = m[r];
            wsL[i * NC2 + chunk] = l[r];
        }
    }
}

// ---------------------------------------------------------------------------
// Kernel 2: TABLE BUILD (G=256 grid) + lse + fused last-block T-reduction.
// 2048 blocks: tgroup = bid>>5 (4 t's), chunk = bid&31 (64-j window);
// wave wv sweeps 16 j for the 4 t's. Partials -> LDS (4KB), 4-way reduce,
// plain stores into accS[chunk][t][d]. Fence-counter: the LAST block of
// each t-group reduces its 32 slices -> T (overlaps other blocks' lse).
// Wave 0 runs one r17-style lse unit (lw = bid).
// ---------------------------------------------------------------------------
__global__ __launch_bounds__(256) void k_mega(
    const uint2* __restrict__ packhg, float* __restrict__ accS,
    float* __restrict__ T, int* __restrict__ cnt,
    const unsigned short* __restrict__ Zx, const unsigned short* __restrict__ Wt,
    const float* __restrict__ QQ, float* __restrict__ wsM, float* __restrict__ wsL)
{
    __shared__ float lds[4][4 * 64];                // 4KB
    __shared__ int ticket;
    int tid  = threadIdx.x;
    int wv   = tid >> 6, lane = tid & 63;
    int bid  = blockIdx.x;
    int chunk = bid & (NCH - 1);
    int tg    = bid >> 5;
    int t0    = tg * 4;
    int j0    = chunk * 64 + wv * 16;

    v2f zt[2], zt2[2], ap[2];
#pragma unroll
    for (int kp = 0; kp < 2; ++kp) {
        float za = ZLO + (float)(t0 + 2 * kp) * DZ;
        float zb = ZLO + (float)(t0 + 2 * kp + 1) * DZ;
        zt[kp]  = (v2f){za, zb};
        zt2[kp] = (v2f){za * za, zb * zb};
        ap[kp]  = (v2f){0.0f, 0.0f};
    }

#pragma unroll 4
    for (int j = j0; j < j0 + 16; ++j) {
        uint2 p = packhg[j * D + lane];
        float h = __uint_as_float(p.x & 0xFFFF0000u);
        float g = __uint_as_float(p.x << 16);
        float q = __uint_as_float(p.y);
        v2f hh = (v2f){h, h};
        v2f gg = (v2f){g, g};
        v2f qq = (v2f){q, q};
#pragma unroll
        for (int kp = 0; kp < 2; ++kp) {
            v2f arg = zt2[kp] * hh + (zt[kp] * gg + qq);  // 2x v_pk_fma_f32
            v2f e;
            e.x = exp2fast(arg.x);
            e.y = exp2fast(arg.y);
            ap[kp] += e;                                  // v_pk_add_f32
        }
    }

#pragma unroll
    for (int kp = 0; kp < 2; ++kp) {
        lds[wv][(2 * kp) * 64 + lane]     = ap[kp].x;
        lds[wv][(2 * kp + 1) * 64 + lane] = ap[kp].y;
    }
    __syncthreads();
    // 4-way reduce; thread tid owns one of the 4t x 64d = 256 elements
    accS[(size_t)chunk * G * D + (size_t)t0 * D + tid] =
        lds[0][tid] + lds[1][tid] + lds[2][tid] + lds[3][tid];

    __threadfence();                   // slice stores visible device-wide
    __syncthreads();
    if (tid == 0) ticket = atomicAdd(&cnt[tg], 1);

    if (wv == 0)
        role_lse(bid, Zx, Wt, QQ, wsM, wsL);   // 2048 units, 1 per block

    __syncthreads();
    if (ticket == NCH - 1) {           // last block of this t-group: reduce
        __threadfence();               // acquire other blocks' slice stores
        float s = 0.0f;
#pragma unroll
        for (int c = 0; c < NCH; ++c)
            s += accS[(size_t)c * G * D + (size_t)t0 * D + tid];
        T[(size_t)t0 * D + tid] = log2fast(s);
    }
}

// ---------------------------------------------------------------------------
// Kernel 3: per-i finalization, one wave per i. lane owns d: Catmull-Rom
// interpolation of T at z[i][d] -> log2 F_d(z_id); butterfly-sum -> lqp2.
// Then the 16-chunk (M,L) merge, kl fold, one atomic per block.
// ---------------------------------------------------------------------------
__global__ __launch_bounds__(256) void k_fin(
    const float* __restrict__ z, const float* __restrict__ T,
    const float* __restrict__ wsM, const float* __restrict__ wsL,
    const float* __restrict__ klp, float* __restrict__ out)
{
    const float LN2 = 0.6931471805599453f;
    __shared__ float red[4];
    int lane = threadIdx.x & 63;
    int wv   = threadIdx.x >> 6;
    int i    = blockIdx.x * 4 + wv;

    float zv = z[i * D + lane];
    float tf = (zv - ZLO) * INVDZ;
    int   it = (int)floorf(tf);
    it = min(max(it, 1), G - 3);
    float u = tf - (float)it;
    float y0 = T[(it - 1) * D + lane];
    float y1 = T[it * D + lane];
    float y2 = T[(it + 1) * D + lane];
    float y3 = T[(it + 2) * D + lane];
    float ca = fmaf(1.5f, y1 - y2, 0.5f * (y3 - y0));
    float cb = y0 - 2.5f * y1 + 2.0f * y2 - 0.5f * y3;
    float cc = 0.5f * (y2 - y0);
    float lqp2 = fmaf(fmaf(fmaf(ca, u, cb), u, cc), u, y1);
#pragma unroll
    for (int off = 32; off; off >>= 1) lqp2 += __shfl_xor(lqp2, off);

    float m = -3.0e38f, l = 0.0f;
    if (lane < NC2) { m = wsM[i * NC2 + lane]; l = wsL[i * NC2 + lane]; }
#pragma unroll
    for (int off = 32; off; off >>= 1) {
        float m2 = __shfl_xor(m, off);
        float l2 = __shfl_xor(l, off);
        float M  = fmaxf(m, m2);
        l = fmaf(l, exp2fast(m - M), l2 * exp2fast(m2 - M));
        m = M;
    }

    if (lane == 0)
        red[wv] = (m + log2fast(l) - lqp2) * LN2;
    __syncthreads();
    if (threadIdx.x == 0)
        atomicAdd(out, (red[0] + red[1] + red[2] + red[3]) * (5.0f / 2048.0f)
                       + klp[blockIdx.x]);
}

// ---------------------------------------------------------------------------
extern "C" void kernel_launch(void* const* d_in, const int* in_sizes, int n_in,
                              void* d_out, int out_size, void* d_ws, size_t ws_size,
                              hipStream_t stream)
{
    const float* kl  = (const float*)d_in[0];
    const float* zm  = (const float*)d_in[1];
    const float* zlv = (const float*)d_in[2];
    const float* zs  = (const float*)d_in[3];
    float* out = (float*)d_out;
    float* ws  = (float*)d_ws;

    // workspace layout (float offsets) — total ~3.5MB
    uint2*          packhg = (uint2*)ws;                         // 2*B*D floats
    unsigned short* Zx   = (unsigned short*)(ws + 2 * B * D);    // B*D floats
    unsigned short* Wt   = (unsigned short*)(ws + 3 * B * D);    // B*D floats
    float*          QQ   = ws + 4 * B * D;                       // B
    float*          wsM  = QQ + B;                               // B*NC2
    float*          wsL  = wsM + (size_t)B * NC2;                // B*NC2
    float*          accS = wsL + (size_t)B * NC2;                // NCH*G*D
    float*          T    = accS + (size_t)NCH * G * D;           // G*D
    float*          klp  = T + (size_t)G * D;                    // 512
    int*            cnt  = (int*)(klp + 512);                    // NTG

    k_pre<<<B / 4, 256, 0, stream>>>(kl, zm, zlv, zs, packhg, Zx, Wt, QQ, klp, cnt, out);
    k_mega<<<NBLK, 256, 0, stream>>>(packhg, accS, T, cnt, Zx, Wt, QQ, wsM, wsL);
    k_fin<<<B / 4, 256, 0, stream>>>(zs, T, wsM, wsL, klp, out);
}

// Round 21
// 37.556 us; speedup vs baseline: 5.6817x; 5.6817x over previous
//
#include <hip/hip_runtime.h>
#include <math.h>

#define B 2048
#define D 64
#define G 256           // z-grid points for the F_d(z) table
#define NCH 32          // j-chunks for the table build
#define NC2 16          // j-chunks for the MFMA/LSE role (128 j each)
#define NBLK 2048       // (G/4) tgroups x 32 chunks

#define ZLO (-5.5f)
#define DZ  (11.0f / 255.0f)
#define INVDZ (255.0f / 11.0f)

typedef float v2f  __attribute__((ext_vector_type(2)));
typedef short bf16x8 __attribute__((ext_vector_type(8)));
typedef float f32x4  __attribute__((ext_vector_type(4)));

static __device__ __forceinline__ float exp2fast(float x) { return __builtin_amdgcn_exp2f(x); }
static __device__ __forceinline__ float log2fast(float x) { return __builtin_amdgcn_logf(x); }
static __device__ __forceinline__ unsigned short f2bf(float x) {
    unsigned u = __float_as_uint(x);
    u += 0x7fff + ((u >> 16) & 1);          // RNE; inputs are finite
    return (unsigned short)(u >> 16);
}

// ---------------------------------------------------------------------------
// Kernel 1: per-(j,d) constants (log2 units):  lp2 = h*z^2 + g*z + q
//   h = -0.5*log2e*exp(-lv), g = -2*mu*h, q = mu^2*h + c
// packhg[j*D+d] = { bf16(h)<<16 | bf16(g), fp32 q }  (8B)
// Zx/Wt = bf16 MFMA operands; QQ[j]=sum_d q; kl partials -> klp; out zeroed.
// ---------------------------------------------------------------------------
__global__ __launch_bounds__(256) void k_pre(
    const float* __restrict__ kl, const float* __restrict__ zm,
    const float* __restrict__ zlv, const float* __restrict__ zs,
    uint2* __restrict__ packhg, unsigned short* __restrict__ Zx,
    unsigned short* __restrict__ Wt, float* __restrict__ QQ,
    float* __restrict__ klp, float* __restrict__ out)
{
    const float LOG2E   = 1.4426950408889634f;
    const float LOG_2PI = 1.8378770664093453f;
    __shared__ float red[4];
    int wv = threadIdx.x >> 6, d = threadIdx.x & 63;
    int j = blockIdx.x * 4 + wv;
    int idx = j * D + d;
    float lv = zlv[idx];
    float mu = zm[idx];
    float zz = zs[idx];
    float is = exp2fast(-LOG2E * lv);            // e^{-lv}
    float h  = -0.5f * LOG2E * is;
    float cv = -0.5f * LOG2E * (lv + LOG_2PI);
    float g  = -2.0f * mu * h;
    float q  = fmaf(mu * mu, h, cv);
    packhg[idx] = make_uint2(((unsigned)f2bf(h) << 16) | f2bf(g),
                             __float_as_uint(q));
    Wt[j * 128 + d]      = f2bf(h);
    Wt[j * 128 + 64 + d] = f2bf(g);
    Zx[j * 128 + d]      = f2bf(zz * zz);
    Zx[j * 128 + 64 + d] = f2bf(zz);

    float qs = q, ks = kl[idx];
#pragma unroll
    for (int off = 32; off; off >>= 1) {
        qs += __shfl_xor(qs, off);
        ks += __shfl_xor(ks, off);
    }
    if (d == 0) { QQ[j] = qs; red[wv] = ks; }
    __syncthreads();
    if (threadIdx.x == 0) {
        klp[blockIdx.x] = red[0] + red[1] + red[2] + red[3];  // kl partial
        if (blockIdx.x == 0) out[0] = 0.0f;                   // zero output
    }
}

// ---------------------------------------------------------------------------
// Role B (lse) — r17-proven, UNTOUCHED: one wave = 16-i x 128-j unit
// (NC2=16, 2048 units, wave 0 of each block). 8 j-tiles x 4 K-steps MFMA,
// online row-LSE, 16-lane butterfly.
// C/D: col = lane&15 (j), row = (lane>>4)*4 + reg (i)  [m89-verified].
// ---------------------------------------------------------------------------
static __device__ __forceinline__ void role_lse(
    int lw, const unsigned short* __restrict__ Zx,
    const unsigned short* __restrict__ Wt, const float* __restrict__ QQ,
    float* __restrict__ wsM, float* __restrict__ wsL)
{
    int lane  = threadIdx.x & 63;
    int i0    = (lw >> 4) * 16;
    int chunk = lw & 15;               // 0..15
    int jbase = chunk * 128;
    int r16 = lane & 15, kg = lane >> 4;

    const bf16x8* Za = (const bf16x8*)(Zx + (size_t)(i0 + r16) * 128 + kg * 8);
    bf16x8 a[4];
#pragma unroll
    for (int s = 0; s < 4; ++s) a[s] = Za[s * 4];   // stride 32 bf16 per K-step

    float m[4], l[4];
#pragma unroll
    for (int r = 0; r < 4; ++r) { m[r] = -3.0e38f; l[r] = 0.0f; }

    for (int t = 0; t < 8; ++t) {
        int j = jbase + t * 16 + r16;
        const bf16x8* Wb = (const bf16x8*)(Wt + (size_t)j * 128 + kg * 8);
        f32x4 c = (f32x4){0.0f, 0.0f, 0.0f, 0.0f};
#pragma unroll
        for (int s = 0; s < 4; ++s)
            c = __builtin_amdgcn_mfma_f32_16x16x32_bf16(a[s], Wb[s * 4], c, 0, 0, 0);
        float qq = QQ[j];
#pragma unroll
        for (int r = 0; r < 4; ++r) {
            float val = c[r] + qq;
            float delta = val - m[r];
            float e = exp2fast(-fabsf(delta));
            l[r] = (delta <= 0.0f) ? (l[r] + e) : fmaf(l[r], e, 1.0f);
            m[r] = fmaxf(m[r], val);
        }
    }
#pragma unroll
    for (int off = 8; off; off >>= 1) {
#pragma unroll
        for (int r = 0; r < 4; ++r) {
            float m2 = __shfl_xor(m[r], off);
            float l2 = __shfl_xor(l[r], off);
            float M  = fmaxf(m[r], m2);
            l[r] = fmaf(l[r], exp2fast(m[r] - M), l2 * exp2fast(m2 - M));
            m[r] = M;
        }
    }
    if (r16 == 0) {
#pragma unroll
        for (int r = 0; r < 4; ++r) {
            int i = i0 + kg * 4 + r;
            wsM[i * NC2 + chunk] = m[r];
            wsL[i * NC2 + chunk] = l[r];
        }
    }
}

// ---------------------------------------------------------------------------
// Kernel 2: TABLE BUILD (G=256) + lse. 2048 uniform blocks: tgroup = bid>>5
// (4 t's), chunk = bid&31 (64-j window); wave wv sweeps 16 j for the 4 t's.
// Partials -> LDS (4KB), 4-way reduce, plain stores into accS[chunk][t][d]
// (zero atomics, no fences). Wave 0 then runs one r17 lse unit (lw = bid).
// ---------------------------------------------------------------------------
__global__ __launch_bounds__(256) void k_mega(
    const uint2* __restrict__ packhg, float* __restrict__ accS,
    const unsigned short* __restrict__ Zx, const unsigned short* __restrict__ Wt,
    const float* __restrict__ QQ, float* __restrict__ wsM, float* __restrict__ wsL)
{
    __shared__ float lds[4][4 * 64];                // 4KB
    int tid  = threadIdx.x;
    int wv   = tid >> 6, lane = tid & 63;
    int bid  = blockIdx.x;
    int chunk = bid & (NCH - 1);
    int t0    = (bid >> 5) * 4;
    int j0    = chunk * 64 + wv * 16;

    v2f zt[2], zt2[2], ap[2];
#pragma unroll
    for (int kp = 0; kp < 2; ++kp) {
        float za = ZLO + (float)(t0 + 2 * kp) * DZ;
        float zb = ZLO + (float)(t0 + 2 * kp + 1) * DZ;
        zt[kp]  = (v2f){za, zb};
        zt2[kp] = (v2f){za * za, zb * zb};
        ap[kp]  = (v2f){0.0f, 0.0f};
    }

#pragma unroll 4
    for (int j = j0; j < j0 + 16; ++j) {
        uint2 p = packhg[j * D + lane];
        float h = __uint_as_float(p.x & 0xFFFF0000u);
        float g = __uint_as_float(p.x << 16);
        float q = __uint_as_float(p.y);
        v2f hh = (v2f){h, h};
        v2f gg = (v2f){g, g};
        v2f qq = (v2f){q, q};
#pragma unroll
        for (int kp = 0; kp < 2; ++kp) {
            v2f arg = zt2[kp] * hh + (zt[kp] * gg + qq);  // 2x v_pk_fma_f32
            v2f e;
            e.x = exp2fast(arg.x);
            e.y = exp2fast(arg.y);
            ap[kp] += e;                                  // v_pk_add_f32
        }
    }

#pragma unroll
    for (int kp = 0; kp < 2; ++kp) {
        lds[wv][(2 * kp) * 64 + lane]     = ap[kp].x;
        lds[wv][(2 * kp + 1) * 64 + lane] = ap[kp].y;
    }
    __syncthreads();
    // 4-way reduce; thread tid owns one of the 4t x 64d = 256 elements
    accS[(size_t)chunk * G * D + (size_t)t0 * D + tid] =
        lds[0][tid] + lds[1][tid] + lds[2][tid] + lds[3][tid];

    if (wv == 0)
        role_lse(bid, Zx, Wt, QQ, wsM, wsL);   // 2048 units, 1 per block
}

// ---------------------------------------------------------------------------
// Kernel 2b: reduce the 32 chunk slices and take log2 -> T[t*64+d].
// ---------------------------------------------------------------------------
__global__ __launch_bounds__(256) void k_tab(
    const float* __restrict__ accS, float* __restrict__ T)
{
    int e = blockIdx.x * 256 + threadIdx.x;    // 0 .. G*D-1
    float s = 0.0f;
#pragma unroll
    for (int c = 0; c < NCH; ++c)
        s += accS[(size_t)c * G * D + e];
    T[e] = log2fast(s);
}

// ---------------------------------------------------------------------------
// Kernel 3: per-i finalization, one wave per i. lane owns d: Catmull-Rom
// interpolation of T at z[i][d] -> log2 F_d(z_id); butterfly-sum -> lqp2.
// Then the 16-chunk (M,L) merge, kl fold, one atomic per block.
// ---------------------------------------------------------------------------
__global__ __launch_bounds__(256) void k_fin(
    const float* __restrict__ z, const float* __restrict__ T,
    const float* __restrict__ wsM, const float* __restrict__ wsL,
    const float* __restrict__ klp, float* __restrict__ out)
{
    const float LN2 = 0.6931471805599453f;
    __shared__ float red[4];
    int lane = threadIdx.x & 63;
    int wv   = threadIdx.x >> 6;
    int i    = blockIdx.x * 4 + wv;

    float zv = z[i * D + lane];
    float tf = (zv - ZLO) * INVDZ;
    int   it = (int)floorf(tf);
    it = min(max(it, 1), G - 3);
    float u = tf - (float)it;
    float y0 = T[(it - 1) * D + lane];
    float y1 = T[it * D + lane];
    float y2 = T[(it + 1) * D + lane];
    float y3 = T[(it + 2) * D + lane];
    float ca = fmaf(1.5f, y1 - y2, 0.5f * (y3 - y0));
    float cb = y0 - 2.5f * y1 + 2.0f * y2 - 0.5f * y3;
    float cc = 0.5f * (y2 - y0);
    float lqp2 = fmaf(fmaf(fmaf(ca, u, cb), u, cc), u, y1);
#pragma unroll
    for (int off = 32; off; off >>= 1) lqp2 += __shfl_xor(lqp2, off);

    float m = -3.0e38f, l = 0.0f;
    if (lane < NC2) { m = wsM[i * NC2 + lane]; l = wsL[i * NC2 + lane]; }
#pragma unroll
    for (int off = 32; off; off >>= 1) {
        float m2 = __shfl_xor(m, off);
        float l2 = __shfl_xor(l, off);
        float M  = fmaxf(m, m2);
        l = fmaf(l, exp2fast(m - M), l2 * exp2fast(m2 - M));
        m = M;
    }

    if (lane == 0)
        red[wv] = (m + log2fast(l) - lqp2) * LN2;
    __syncthreads();
    if (threadIdx.x == 0)
        atomicAdd(out, (red[0] + red[1] + red[2] + red[3]) * (5.0f / 2048.0f)
                       + klp[blockIdx.x]);
}

// ---------------------------------------------------------------------------
extern "C" void kernel_launch(void* const* d_in, const int* in_sizes, int n_in,
                              void* d_out, int out_size, void* d_ws, size_t ws_size,
                              hipStream_t stream)
{
    const float* kl  = (const float*)d_in[0];
    const float* zm  = (const float*)d_in[1];
    const float* zlv = (const float*)d_in[2];
    const float* zs  = (const float*)d_in[3];
    float* out = (float*)d_out;
    float* ws  = (float*)d_ws;

    // workspace layout (float offsets) — total ~3.5MB
    uint2*          packhg = (uint2*)ws;                         // 2*B*D floats
    unsigned short* Zx   = (unsigned short*)(ws + 2 * B * D);    // B*D floats
    unsigned short* Wt   = (unsigned short*)(ws + 3 * B * D);    // B*D floats
    float*          QQ   = ws + 4 * B * D;                       // B
    float*          wsM  = QQ + B;                               // B*NC2
    float*          wsL  = wsM + (size_t)B * NC2;                // B*NC2
    float*          accS = wsL + (size_t)B * NC2;                // NCH*G*D
    float*          T    = accS + (size_t)NCH * G * D;           // G*D
    float*          klp  = T + (size_t)G * D;                    // 512

    k_pre<<<B / 4, 256, 0, stream>>>(kl, zm, zlv, zs, packhg, Zx, Wt, QQ, klp, out);
    k_mega<<<NBLK, 256, 0, stream>>>(packhg, accS, Zx, Wt, QQ, wsM, wsL);
    k_tab<<<(G * D) / 256, 256, 0, stream>>>(accS, T);
    k_fin<<<B / 4, 256, 0, stream>>>(zs, T, wsM, wsL, klp, out);
}

// Round 22
// 37.339 us; speedup vs baseline: 5.7148x; 1.0058x over previous
//
#include <hip/hip_runtime.h>
#include <math.h>

#define B 2048
#define D 64
#define G 256           // z-grid points for the F_d(z) table
#define NC2 16          // j-chunks for the MFMA/LSE role (128 j each)
#define NBLK 2048
#define NSL 96          // build j-slices (21-22 j each)

#define ZLO (-5.5f)
#define DZ  (11.0f / 255.0f)
#define INVDZ (255.0f / 11.0f)

typedef float v2f  __attribute__((ext_vector_type(2)));
typedef short bf16x8 __attribute__((ext_vector_type(8)));
typedef float f32x4  __attribute__((ext_vector_type(4)));

static __device__ __forceinline__ float exp2fast(float x) { return __builtin_amdgcn_exp2f(x); }
static __device__ __forceinline__ float log2fast(float x) { return __builtin_amdgcn_logf(x); }
static __device__ __forceinline__ unsigned short f2bf(float x) {
    unsigned u = __float_as_uint(x);
    u += 0x7fff + ((u >> 16) & 1);          // RNE; inputs are finite
    return (unsigned short)(u >> 16);
}

// ---------------------------------------------------------------------------
// Kernel 1: per-(j,d) constants (log2 units):  lp2 = h*z^2 + g*z + q
//   h = -0.5*log2e*exp(-lv), g = -2*mu*h, q = mu^2*h + c
// packhg[j*D+d] = { bf16(h)<<16 | bf16(g), fp32 q }  (8B)
// Zx/Wt = bf16 MFMA operands; QQ[j]=sum_d q; kl partials -> klp;
// out zeroed; acc[G*D] zeroed (blocks 0..63).
// ---------------------------------------------------------------------------
__global__ __launch_bounds__(256) void k_pre(
    const float* __restrict__ kl, const float* __restrict__ zm,
    const float* __restrict__ zlv, const float* __restrict__ zs,
    uint2* __restrict__ packhg, unsigned short* __restrict__ Zx,
    unsigned short* __restrict__ Wt, float* __restrict__ QQ,
    float* __restrict__ klp, float* __restrict__ acc, float* __restrict__ out)
{
    const float LOG2E   = 1.4426950408889634f;
    const float LOG_2PI = 1.8378770664093453f;
    __shared__ float red[4];
    int wv = threadIdx.x >> 6, d = threadIdx.x & 63;
    int j = blockIdx.x * 4 + wv;
    int idx = j * D + d;
    if (blockIdx.x < (G * D) / 256)
        acc[blockIdx.x * 256 + threadIdx.x] = 0.0f;   // zero table accumulator
    float lv = zlv[idx];
    float mu = zm[idx];
    float zz = zs[idx];
    float is = exp2fast(-LOG2E * lv);            // e^{-lv}
    float h  = -0.5f * LOG2E * is;
    float cv = -0.5f * LOG2E * (lv + LOG_2PI);
    float g  = -2.0f * mu * h;
    float q  = fmaf(mu * mu, h, cv);
    packhg[idx] = make_uint2(((unsigned)f2bf(h) << 16) | f2bf(g),
                             __float_as_uint(q));
    Wt[j * 128 + d]      = f2bf(h);
    Wt[j * 128 + 64 + d] = f2bf(g);
    Zx[j * 128 + d]      = f2bf(zz * zz);
    Zx[j * 128 + 64 + d] = f2bf(zz);

    float qs = q, ks = kl[idx];
#pragma unroll
    for (int off = 32; off; off >>= 1) {
        qs += __shfl_xor(qs, off);
        ks += __shfl_xor(ks, off);
    }
    if (d == 0) { QQ[j] = qs; red[wv] = ks; }
    __syncthreads();
    if (threadIdx.x == 0) {
        klp[blockIdx.x] = red[0] + red[1] + red[2] + red[3];  // kl partial
        if (blockIdx.x == 0) out[0] = 0.0f;                   // zero output
    }
}

// ---------------------------------------------------------------------------
// Role B (lse) — r17-proven, UNTOUCHED: one wave = 16-i x 128-j unit
// (NC2=16, 2048 units, wave 0 of each block). 8 j-tiles x 4 K-steps MFMA,
// online row-LSE, 16-lane butterfly.
// C/D: col = lane&15 (j), row = (lane>>4)*4 + reg (i)  [m89-verified].
// ---------------------------------------------------------------------------
static __device__ __forceinline__ void role_lse(
    int lw, const unsigned short* __restrict__ Zx,
    const unsigned short* __restrict__ Wt, const float* __restrict__ QQ,
    float* __restrict__ wsM, float* __restrict__ wsL)
{
    int lane  = threadIdx.x & 63;
    int i0    = (lw >> 4) * 16;
    int chunk = lw & 15;               // 0..15
    int jbase = chunk * 128;
    int r16 = lane & 15, kg = lane >> 4;

    const bf16x8* Za = (const bf16x8*)(Zx + (size_t)(i0 + r16) * 128 + kg * 8);
    bf16x8 a[4];
#pragma unroll
    for (int s = 0; s < 4; ++s) a[s] = Za[s * 4];   // stride 32 bf16 per K-step

    float m[4], l[4];
#pragma unroll
    for (int r = 0; r < 4; ++r) { m[r] = -3.0e38f; l[r] = 0.0f; }

    for (int t = 0; t < 8; ++t) {
        int j = jbase + t * 16 + r16;
        const bf16x8* Wb = (const bf16x8*)(Wt + (size_t)j * 128 + kg * 8);
        f32x4 c = (f32x4){0.0f, 0.0f, 0.0f, 0.0f};
#pragma unroll
        for (int s = 0; s < 4; ++s)
            c = __builtin_amdgcn_mfma_f32_16x16x32_bf16(a[s], Wb[s * 4], c, 0, 0, 0);
        float qq = QQ[j];
#pragma unroll
        for (int r = 0; r < 4; ++r) {
            float val = c[r] + qq;
            float delta = val - m[r];
            float e = exp2fast(-fabsf(delta));
            l[r] = (delta <= 0.0f) ? (l[r] + e) : fmaf(l[r], e, 1.0f);
            m[r] = fmaxf(m[r], val);
        }
    }
#pragma unroll
    for (int off = 8; off; off >>= 1) {
#pragma unroll
        for (int r = 0; r < 4; ++r) {
            float m2 = __shfl_xor(m[r], off);
            float l2 = __shfl_xor(l[r], off);
            float M  = fmaxf(m[r], m2);
            l[r] = fmaf(l[r], exp2fast(m[r] - M), l2 * exp2fast(m2 - M));
            m[r] = M;
        }
    }
    if (r16 == 0) {
#pragma unroll
        for (int r = 0; r < 4; ++r) {
            int i = i0 + kg * 4 + r;
            wsM[i * NC2 + chunk] = m[r];
            wsL[i * NC2 + chunk] = l[r];
        }
    }
}

// ---------------------------------------------------------------------------
// Kernel 2: WAVE-SPECIALIZED table build + lse. 2048 uniform 256-thr blocks.
//   wave 0   : one r17 lse unit (lw = bid) — runs CONCURRENTLY with build.
//   waves 1-3: one build cell each: w = bid*3+(wv-1) in [0,6144);
//              tg = w/96 (4 t's), slice = w%96 (21-22 j).
//              F_d partials accumulated in registers over the j-slice,
//              then 4 atomicAdd per lane into acc[t*64+d] (1.57M total).
// No LDS, no barriers; block time = max(lse, build) ~ overlap both.
// ---------------------------------------------------------------------------
__global__ __launch_bounds__(256) void k_mega(
    const uint2* __restrict__ packhg, float* __restrict__ acc,
    const unsigned short* __restrict__ Zx, const unsigned short* __restrict__ Wt,
    const float* __restrict__ QQ, float* __restrict__ wsM, float* __restrict__ wsL)
{
    int tid  = threadIdx.x;
    int wv   = tid >> 6, lane = tid & 63;
    int bid  = blockIdx.x;

    if (wv == 0) {
        role_lse(bid, Zx, Wt, QQ, wsM, wsL);   // 2048 units, 1 per block
        return;
    }

    int w     = bid * 3 + (wv - 1);            // 0..6143
    int tg    = w / 96;                        // 0..63
    int slice = w - tg * 96;                   // 0..95
    int t0    = tg * 4;
    int nj    = 21 + (slice < 32 ? 1 : 0);
    int j0    = slice * 21 + min(slice, 32);

    v2f zt[2], zt2[2], ap[2];
#pragma unroll
    for (int kp = 0; kp < 2; ++kp) {
        float za = ZLO + (float)(t0 + 2 * kp) * DZ;
        float zb = ZLO + (float)(t0 + 2 * kp + 1) * DZ;
        zt[kp]  = (v2f){za, zb};
        zt2[kp] = (v2f){za * za, zb * zb};
        ap[kp]  = (v2f){0.0f, 0.0f};
    }

#pragma unroll 4
    for (int j = j0; j < j0 + nj; ++j) {
        uint2 p = packhg[j * D + lane];
        float h = __uint_as_float(p.x & 0xFFFF0000u);
        float g = __uint_as_float(p.x << 16);
        float q = __uint_as_float(p.y);
        v2f hh = (v2f){h, h};
        v2f gg = (v2f){g, g};
        v2f qq = (v2f){q, q};
#pragma unroll
        for (int kp = 0; kp < 2; ++kp) {
            v2f arg = zt2[kp] * hh + (zt[kp] * gg + qq);  // 2x v_pk_fma_f32
            v2f e;
            e.x = exp2fast(arg.x);
            e.y = exp2fast(arg.y);
            ap[kp] += e;                                  // v_pk_add_f32
        }
    }

#pragma unroll
    for (int kp = 0; kp < 2; ++kp) {
        atomicAdd(&acc[(t0 + 2 * kp) * D + lane],     ap[kp].x);
        atomicAdd(&acc[(t0 + 2 * kp + 1) * D + lane], ap[kp].y);
    }
}

// ---------------------------------------------------------------------------
// Kernel 3: per-i finalization, one wave per i. lane owns d: Catmull-Rom
// interpolation of log2(acc) at z[i][d] (log2 taken inline — k_tab dispatch
// eliminated); butterfly-sum -> lqp2. Then the 16-chunk (M,L) merge, kl
// fold, one atomic per block.
// ---------------------------------------------------------------------------
__global__ __launch_bounds__(256) void k_fin(
    const float* __restrict__ z, const float* __restrict__ acc,
    const float* __restrict__ wsM, const float* __restrict__ wsL,
    const float* __restrict__ klp, float* __restrict__ out)
{
    const float LN2 = 0.6931471805599453f;
    __shared__ float red[4];
    int lane = threadIdx.x & 63;
    int wv   = threadIdx.x >> 6;
    int i    = blockIdx.x * 4 + wv;

    float zv = z[i * D + lane];
    float tf = (zv - ZLO) * INVDZ;
    int   it = (int)floorf(tf);
    it = min(max(it, 1), G - 3);
    float u = tf - (float)it;
    float y0 = log2fast(acc[(it - 1) * D + lane]);
    float y1 = log2fast(acc[it * D + lane]);
    float y2 = log2fast(acc[(it + 1) * D + lane]);
    float y3 = log2fast(acc[(it + 2) * D + lane]);
    float ca = fmaf(1.5f, y1 - y2, 0.5f * (y3 - y0));
    float cb = y0 - 2.5f * y1 + 2.0f * y2 - 0.5f * y3;
    float cc = 0.5f * (y2 - y0);
    float lqp2 = fmaf(fmaf(fmaf(ca, u, cb), u, cc), u, y1);
#pragma unroll
    for (int off = 32; off; off >>= 1) lqp2 += __shfl_xor(lqp2, off);

    float m = -3.0e38f, l = 0.0f;
    if (lane < NC2) { m = wsM[i * NC2 + lane]; l = wsL[i * NC2 + lane]; }
#pragma unroll
    for (int off = 32; off; off >>= 1) {
        float m2 = __shfl_xor(m, off);
        float l2 = __shfl_xor(l, off);
        float M  = fmaxf(m, m2);
        l = fmaf(l, exp2fast(m - M), l2 * exp2fast(m2 - M));
        m = M;
    }

    if (lane == 0)
        red[wv] = (m + log2fast(l) - lqp2) * LN2;
    __syncthreads();
    if (threadIdx.x == 0)
        atomicAdd(out, (red[0] + red[1] + red[2] + red[3]) * (5.0f / 2048.0f)
                       + klp[blockIdx.x]);
}

// ---------------------------------------------------------------------------
extern "C" void kernel_launch(void* const* d_in, const int* in_sizes, int n_in,
                              void* d_out, int out_size, void* d_ws, size_t ws_size,
                              hipStream_t stream)
{
    const float* kl  = (const float*)d_in[0];
    const float* zm  = (const float*)d_in[1];
    const float* zlv = (const float*)d_in[2];
    const float* zs  = (const float*)d_in[3];
    float* out = (float*)d_out;
    float* ws  = (float*)d_ws;

    // workspace layout (float offsets) — total ~3.3MB
    uint2*          packhg = (uint2*)ws;                         // 2*B*D floats
    unsigned short* Zx   = (unsigned short*)(ws + 2 * B * D);    // B*D floats
    unsigned short* Wt   = (unsigned short*)(ws + 3 * B * D);    // B*D floats
    float*          QQ   = ws + 4 * B * D;                       // B
    float*          wsM  = QQ + B;                               // B*NC2
    float*          wsL  = wsM + (size_t)B * NC2;                // B*NC2
    float*          acc  = wsL + (size_t)B * NC2;                // G*D
    float*          klp  = acc + (size_t)G * D;                  // 512

    k_pre<<<B / 4, 256, 0, stream>>>(kl, zm, zlv, zs, packhg, Zx, Wt, QQ, klp, acc, out);
    k_mega<<<NBLK, 256, 0, stream>>>(packhg, acc, Zx, Wt, QQ, wsM, wsL);
    k_fin<<<B / 4, 256, 0, stream>>>(zs, acc, wsM, wsL, klp, out);
}

// Round 23
// 36.353 us; speedup vs baseline: 5.8699x; 1.0271x over previous
//
#include <hip/hip_runtime.h>
#include <math.h>

#define B 2048
#define D 64
#define G 128           // z-grid points for the F_d(z) table
#define NC2 16          // j-chunks for the MFMA/LSE role (128 j each)
#define NBLK 2048

#define ZLO (-5.5f)
#define DZ  (11.0f / 127.0f)
#define INVDZ (127.0f / 11.0f)

typedef float v2f  __attribute__((ext_vector_type(2)));
typedef short bf16x8 __attribute__((ext_vector_type(8)));
typedef float f32x4  __attribute__((ext_vector_type(4)));

static __device__ __forceinline__ float exp2fast(float x) { return __builtin_amdgcn_exp2f(x); }
static __device__ __forceinline__ float log2fast(float x) { return __builtin_amdgcn_logf(x); }
static __device__ __forceinline__ unsigned short f2bf(float x) {
    unsigned u = __float_as_uint(x);
    u += 0x7fff + ((u >> 16) & 1);          // RNE; inputs are finite
    return (unsigned short)(u >> 16);
}

// ---------------------------------------------------------------------------
// Kernel 1: per-(j,d) constants (log2 units):  lp2 = h*z^2 + g*z + q
//   h = -0.5*log2e*exp(-lv), g = -2*mu*h, q = mu^2*h + c
// packhg[j*D+d] = { bf16(h)<<16 | bf16(g), fp32 q }  (8B)
// Zx/Wt = bf16 MFMA operands; QQ[j]=sum_d q; kl partials -> klp;
// out zeroed; acc[G*D] zeroed (blocks 0..31).
// ---------------------------------------------------------------------------
__global__ __launch_bounds__(256) void k_pre(
    const float* __restrict__ kl, const float* __restrict__ zm,
    const float* __restrict__ zlv, const float* __restrict__ zs,
    uint2* __restrict__ packhg, unsigned short* __restrict__ Zx,
    unsigned short* __restrict__ Wt, float* __restrict__ QQ,
    float* __restrict__ klp, float* __restrict__ acc, float* __restrict__ out)
{
    const float LOG2E   = 1.4426950408889634f;
    const float LOG_2PI = 1.8378770664093453f;
    __shared__ float red[4];
    int wv = threadIdx.x >> 6, d = threadIdx.x & 63;
    int j = blockIdx.x * 4 + wv;
    int idx = j * D + d;
    if (blockIdx.x < (G * D) / 256)
        acc[blockIdx.x * 256 + threadIdx.x] = 0.0f;   // zero table accumulator
    float lv = zlv[idx];
    float mu = zm[idx];
    float zz = zs[idx];
    float is = exp2fast(-LOG2E * lv);            // e^{-lv}
    float h  = -0.5f * LOG2E * is;
    float cv = -0.5f * LOG2E * (lv + LOG_2PI);
    float g  = -2.0f * mu * h;
    float q  = fmaf(mu * mu, h, cv);
    packhg[idx] = make_uint2(((unsigned)f2bf(h) << 16) | f2bf(g),
                             __float_as_uint(q));
    Wt[j * 128 + d]      = f2bf(h);
    Wt[j * 128 + 64 + d] = f2bf(g);
    Zx[j * 128 + d]      = f2bf(zz * zz);
    Zx[j * 128 + 64 + d] = f2bf(zz);

    float qs = q, ks = kl[idx];
#pragma unroll
    for (int off = 32; off; off >>= 1) {
        qs += __shfl_xor(qs, off);
        ks += __shfl_xor(ks, off);
    }
    if (d == 0) { QQ[j] = qs; red[wv] = ks; }
    __syncthreads();
    if (threadIdx.x == 0) {
        klp[blockIdx.x] = red[0] + red[1] + red[2] + red[3];  // kl partial
        if (blockIdx.x == 0) out[0] = 0.0f;                   // zero output
    }
}

// ---------------------------------------------------------------------------
// Role B (lse), r17 structure + B-fragment DOUBLE-BUFFER: one wave = 16-i x
// 128-j unit (NC2=16, 2048 units, wave 0 of each block). The 8 j-tiles'
// B-fragments are prefetched one tile ahead (t-loop fully unrolled) so the
// ~200cy L2 load latency hides under the previous tile's MFMA+LSE compute.
// C/D: col = lane&15 (j), row = (lane>>4)*4 + reg (i)  [m89-verified].
// ---------------------------------------------------------------------------
static __device__ __forceinline__ void role_lse(
    int lw, const unsigned short* __restrict__ Zx,
    const unsigned short* __restrict__ Wt, const float* __restrict__ QQ,
    float* __restrict__ wsM, float* __restrict__ wsL)
{
    int lane  = threadIdx.x & 63;
    int i0    = (lw >> 4) * 16;
    int chunk = lw & 15;               // 0..15
    int jbase = chunk * 128;
    int r16 = lane & 15, kg = lane >> 4;

    const bf16x8* Za = (const bf16x8*)(Zx + (size_t)(i0 + r16) * 128 + kg * 8);
    bf16x8 a[4];
#pragma unroll
    for (int s = 0; s < 4; ++s) a[s] = Za[s * 4];   // stride 32 bf16 per K-step

    // B-fragment base for this lane: row (jbase + r16), K-offset kg*8.
    // Tile t fragment s lives at +t*256 + s*4 (bf16x8 units).
    const bf16x8* Wb = (const bf16x8*)(Wt + (size_t)(jbase + r16) * 128 + kg * 8);

    float m[4], l[4];
#pragma unroll
    for (int r = 0; r < 4; ++r) { m[r] = -3.0e38f; l[r] = 0.0f; }

    bf16x8 bb[2][4];
#pragma unroll
    for (int s = 0; s < 4; ++s) bb[0][s] = Wb[s * 4];
    float qq_c = QQ[jbase + r16];

#pragma unroll
    for (int t = 0; t < 8; ++t) {
        int cur = t & 1, nxt = cur ^ 1;
        float qq_n = 0.0f;
        if (t < 7) {
#pragma unroll
            for (int s = 0; s < 4; ++s) bb[nxt][s] = Wb[(t + 1) * 256 + s * 4];
            qq_n = QQ[jbase + (t + 1) * 16 + r16];
        }
        f32x4 c = (f32x4){0.0f, 0.0f, 0.0f, 0.0f};
#pragma unroll
        for (int s = 0; s < 4; ++s)
            c = __builtin_amdgcn_mfma_f32_16x16x32_bf16(a[s], bb[cur][s], c, 0, 0, 0);
#pragma unroll
        for (int r = 0; r < 4; ++r) {
            float val = c[r] + qq_c;
            float delta = val - m[r];
            float e = exp2fast(-fabsf(delta));
            l[r] = (delta <= 0.0f) ? (l[r] + e) : fmaf(l[r], e, 1.0f);
            m[r] = fmaxf(m[r], val);
        }
        qq_c = qq_n;
    }
#pragma unroll
    for (int off = 8; off; off >>= 1) {
#pragma unroll
        for (int r = 0; r < 4; ++r) {
            float m2 = __shfl_xor(m[r], off);
            float l2 = __shfl_xor(l[r], off);
            float M  = fmaxf(m[r], m2);
            l[r] = fmaf(l[r], exp2fast(m[r] - M), l2 * exp2fast(m2 - M));
            m[r] = M;
        }
    }
    if (r16 == 0) {
#pragma unroll
        for (int r = 0; r < 4; ++r) {
            int i = i0 + kg * 4 + r;
            wsM[i * NC2 + chunk] = m[r];
            wsL[i * NC2 + chunk] = l[r];
        }
    }
}

// ---------------------------------------------------------------------------
// Kernel 2: WAVE-SPECIALIZED table build + lse. 2048 uniform 256-thr blocks.
//   wave 0   : one lse unit (lw = bid) — runs CONCURRENTLY with build.
//   waves 1-3: one build cell each: w = bid*3+(wv-1) in [0,6144);
//              tg = w/96 (2 t's), slice = w%96 (21-22 j).
//              F_d partials in registers over the j-slice, then 2 atomicAdd
//              per lane into acc[t*64+d].
// No LDS, no barriers; block time = max(lse, build).
// ---------------------------------------------------------------------------
__global__ __launch_bounds__(256) void k_mega(
    const uint2* __restrict__ packhg, float* __restrict__ acc,
    const unsigned short* __restrict__ Zx, const unsigned short* __restrict__ Wt,
    const float* __restrict__ QQ, float* __restrict__ wsM, float* __restrict__ wsL)
{
    int tid  = threadIdx.x;
    int wv   = tid >> 6, lane = tid & 63;
    int bid  = blockIdx.x;

    if (wv == 0) {
        role_lse(bid, Zx, Wt, QQ, wsM, wsL);   // 2048 units, 1 per block
        return;
    }

    int w     = bid * 3 + (wv - 1);            // 0..6143
    int tg    = w / 96;                        // 0..63
    int slice = w - tg * 96;                   // 0..95
    int t0    = tg * 2;
    int nj    = 21 + (slice < 32 ? 1 : 0);
    int j0    = slice * 21 + min(slice, 32);

    float za = ZLO + (float)t0 * DZ;
    float zb = ZLO + (float)(t0 + 1) * DZ;
    v2f zt  = (v2f){za, zb};
    v2f zt2 = (v2f){za * za, zb * zb};
    v2f ap  = (v2f){0.0f, 0.0f};

#pragma unroll 4
    for (int j = j0; j < j0 + nj; ++j) {
        uint2 p = packhg[j * D + lane];
        float h = __uint_as_float(p.x & 0xFFFF0000u);
        float g = __uint_as_float(p.x << 16);
        float q = __uint_as_float(p.y);
        v2f arg = zt2 * (v2f){h, h} + (zt * (v2f){g, g} + (v2f){q, q});
        v2f e;
        e.x = exp2fast(arg.x);
        e.y = exp2fast(arg.y);
        ap += e;
    }

    atomicAdd(&acc[t0 * D + lane],       ap.x);
    atomicAdd(&acc[(t0 + 1) * D + lane], ap.y);
}

// ---------------------------------------------------------------------------
// Kernel 3: per-i finalization, one wave per i. lane owns d: Catmull-Rom
// interpolation of log2(acc) at z[i][d]; butterfly-sum -> lqp2. Then the
// 16-chunk (M,L) merge, kl fold, one atomic per block.
// ---------------------------------------------------------------------------
__global__ __launch_bounds__(256) void k_fin(
    const float* __restrict__ z, const float* __restrict__ acc,
    const float* __restrict__ wsM, const float* __restrict__ wsL,
    const float* __restrict__ klp, float* __restrict__ out)
{
    const float LN2 = 0.6931471805599453f;
    __shared__ float red[4];
    int lane = threadIdx.x & 63;
    int wv   = threadIdx.x >> 6;
    int i    = blockIdx.x * 4 + wv;

    float zv = z[i * D + lane];
    float tf = (zv - ZLO) * INVDZ;
    int   it = (int)floorf(tf);
    it = min(max(it, 1), G - 3);
    float u = tf - (float)it;
    float y0 = log2fast(acc[(it - 1) * D + lane]);
    float y1 = log2fast(acc[it * D + lane]);
    float y2 = log2fast(acc[(it + 1) * D + lane]);
    float y3 = log2fast(acc[(it + 2) * D + lane]);
    float ca = fmaf(1.5f, y1 - y2, 0.5f * (y3 - y0));
    float cb = y0 - 2.5f * y1 + 2.0f * y2 - 0.5f * y3;
    float cc = 0.5f * (y2 - y0);
    float lqp2 = fmaf(fmaf(fmaf(ca, u, cb), u, cc), u, y1);
#pragma unroll
    for (int off = 32; off; off >>= 1) lqp2 += __shfl_xor(lqp2, off);

    float m = -3.0e38f, l = 0.0f;
    if (lane < NC2) { m = wsM[i * NC2 + lane]; l = wsL[i * NC2 + lane]; }
#pragma unroll
    for (int off = 32; off; off >>= 1) {
        float m2 = __shfl_xor(m, off);
        float l2 = __shfl_xor(l, off);
        float M  = fmaxf(m, m2);
        l = fmaf(l, exp2fast(m - M), l2 * exp2fast(m2 - M));
        m = M;
    }

    if (lane == 0)
        red[wv] = (m + log2fast(l) - lqp2) * LN2;
    __syncthreads();
    if (threadIdx.x == 0)
        atomicAdd(out, (red[0] + red[1] + red[2] + red[3]) * (5.0f / 2048.0f)
                       + klp[blockIdx.x]);
}

// ---------------------------------------------------------------------------
extern "C" void kernel_launch(void* const* d_in, const int* in_sizes, int n_in,
                              void* d_out, int out_size, void* d_ws, size_t ws_size,
                              hipStream_t stream)
{
    const float* kl  = (const float*)d_in[0];
    const float* zm  = (const float*)d_in[1];
    const float* zlv = (const float*)d_in[2];
    const float* zs  = (const float*)d_in[3];
    float* out = (float*)d_out;
    float* ws  = (float*)d_ws;

    // workspace layout (float offsets) — total ~3.3MB
    uint2*          packhg = (uint2*)ws;                         // 2*B*D floats
    unsigned short* Zx   = (unsigned short*)(ws + 2 * B * D);    // B*D floats
    unsigned short* Wt   = (unsigned short*)(ws + 3 * B * D);    // B*D floats
    float*          QQ   = ws + 4 * B * D;                       // B
    float*          wsM  = QQ + B;                               // B*NC2
    float*          wsL  = wsM + (size_t)B * NC2;                // B*NC2
    float*          acc  = wsL + (size_t)B * NC2;                // G*D
    float*          klp  = acc + (size_t)G * D;                  // 512

    k_pre<<<B / 4, 256, 0, stream>>>(kl, zm, zlv, zs, packhg, Zx, Wt, QQ, klp, acc, out);
    k_mega<<<NBLK, 256, 0, stream>>>(packhg, acc, Zx, Wt, QQ, wsM, wsL);
    k_fin<<<B / 4, 256, 0, stream>>>(zs, acc, wsM, wsL, klp, out);
}